// Round 13
// baseline (211.544 us; speedup 1.0000x reference)
//
#include <hip/hip_runtime.h>
#include <hip/hip_bf16.h>

#define B_   4
#define T_   2048
#define C_   1024
#define H_   16
#define BT_  (B_ * T_)      // 8192
#define NQKV (3 * C_)       // 3072

typedef __attribute__((ext_vector_type(8))) short short8;
typedef __attribute__((ext_vector_type(4))) short short4v;
typedef __attribute__((ext_vector_type(4))) float f32x4;

__device__ inline float b2f(short u) {
    unsigned int x = ((unsigned int)(unsigned short)u) << 16;
    float f;
    __builtin_memcpy(&f, &x, 4);
    return f;
}
__device__ inline short f2b(float f) {
    __hip_bfloat16 h = __float2bfloat16(f);
    unsigned short u;
    __builtin_memcpy(&u, &h, 2);
    return (short)u;
}
__device__ inline f32x4 fz4() { f32x4 z; z[0] = z[1] = z[2] = z[3] = 0.f; return z; }
__device__ inline float exp2_raw(float x) {   // bare v_exp_f32 (=2^x), no libm fixup
    float r;
    asm("v_exp_f32 %0, %1" : "=v"(r) : "v"(x));
    return r;
}

__device__ inline void load_lds16(const void* g, void* l) {
    __builtin_amdgcn_global_load_lds((const __attribute__((address_space(1))) unsigned int*)g,
                                     (__attribute__((address_space(3))) unsigned int*)l,
                                     16, 0, 0);
}
__device__ inline void barrier_nodrain() {
    __builtin_amdgcn_sched_barrier(0);
    __builtin_amdgcn_s_barrier();
    __builtin_amdgcn_sched_barrier(0);
}

// fp32 -> bf16 bulk convert (n multiple of 2048)
__global__ __launch_bounds__(256) void cvt_kernel(const float* __restrict__ in,
                                                  short* __restrict__ out, int n) {
    int i = (blockIdx.x * 256 + threadIdx.x) * 8;
    if (i >= n) return;
    float4 a = *(const float4*)(in + i);
    float4 b = *(const float4*)(in + i + 4);
    short8 s;
    s[0] = f2b(a.x); s[1] = f2b(a.y); s[2] = f2b(a.z); s[3] = f2b(a.w);
    s[4] = f2b(b.x); s[5] = f2b(b.y); s[6] = f2b(b.z); s[7] = f2b(b.w);
    *(short8*)(out + i) = s;
}

// cos/sin table: tab[t*32+i] = (cos, sin) of t * 10000^(-i/32), t<2048, i<32
__global__ __launch_bounds__(256) void rope_table(float2* __restrict__ tab) {
    int idx = blockIdx.x * 256 + threadIdx.x;   // 65536
    int t = idx >> 5, i = idx & 31;
    float inv = exp2f(-(float)i * 0.41524101186092029f);
    float ang = (float)t * inv;
    float s, c;
    sincosf(ang, &s, &c);
    tab[idx] = make_float2(c, s);
}

// C[m][n] = sum_k A[m][k]*Bw[n][k]; A,Bw bf16 [.][K]. 128x256 block, BK=64,
// 8 waves (2Mx4N, 64x64 wave-tile). RING-3 LDS, prefetch distance 2, counted
// vmcnt(6), and a 4-phase fine interleave per K-tile (T3): each phase =
// {ds_reads + gload issue -> barrier -> lgkmcnt(0) -> setprio MFMA x8 -> barrier}.
template <int CF32, int ROPE>
__global__ __launch_bounds__(512) void gemm_pipe(const short* __restrict__ Ab,
                                                 const short* __restrict__ Bw,
                                                 void* __restrict__ Cp,
                                                 int M, int N, int K,
                                                 const float2* __restrict__ tab) {
    __shared__ short As[3][128 * 64];
    __shared__ short Bs[3][256 * 64];
    const int tid = threadIdx.x;
    const int l16 = tid & 15, lq = (tid & 63) >> 4;
    const int wid = tid >> 6;          // 0..7
    const int wm = wid >> 2, wn = wid & 3;   // 2M x 4N wave grid
    const int m0 = blockIdx.x * 128, n0 = blockIdx.y * 256;
    const int NT = K >> 6;

    f32x4 acc[4][4];
#pragma unroll
    for (int i = 0; i < 4; ++i)
#pragma unroll
        for (int j = 0; j < 4; ++j) acc[i][j] = fz4();

    auto stageA = [&](int bf, int t) {   // 2 gload_lds
        const int k0 = t * 64;
#pragma unroll
        for (int p = 0; p < 2; ++p) {
            int c = p * 512 + tid;
            int r = c >> 3, cs = (c & 7) ^ (r & 7);
            load_lds16(Ab + (size_t)(m0 + r) * K + k0 + cs * 8,
                       &As[bf][(p * 512 + (tid & ~63)) * 8]);
        }
    };
    auto stageB = [&](int bf, int t, int p0) {   // 2 gload_lds
        const int k0 = t * 64;
#pragma unroll
        for (int p = 0; p < 2; ++p) {
            int c = (p0 + p) * 512 + tid;
            int r = c >> 3, cs = (c & 7) ^ (r & 7);
            load_lds16(Bw + (size_t)(n0 + r) * K + k0 + cs * 8,
                       &Bs[bf][((p0 + p) * 512 + (tid & ~63)) * 8]);
        }
    };
    auto LDA = [&](const short* Ac, int mf, int kk) -> short8 {
        int row = wm * 64 + mf * 16 + l16;
        return *(const short8*)&Ac[row * 64 + (((kk * 4 + lq) ^ (row & 7)) * 8)];
    };
    auto LDB = [&](const short* Bc, int nf, int kk) -> short8 {
        int row = wn * 64 + nf * 16 + l16;
        return *(const short8*)&Bc[row * 64 + (((kk * 4 + lq) ^ (row & 7)) * 8)];
    };

    stageA(0, 0); stageB(0, 0, 0); stageB(0, 0, 2);
    if (NT > 1) { stageA(1, 1); stageB(1, 1, 0); stageB(1, 1, 2); }
    for (int t = 0; t < NT; ++t) {
        // tile t's 6 loads are the oldest outstanding; t+1's (<=6) may still fly
        if (t + 1 < NT) {
            asm volatile("s_waitcnt vmcnt(6)" ::: "memory");
        } else {
            asm volatile("s_waitcnt vmcnt(0)" ::: "memory");
        }
        barrier_nodrain();               // all waves: tile t resident; iter t-1 reads done
        const short* Ac = As[t % 3];
        const short* Bc = Bs[t % 3];
        const int t2 = t + 2;
        const bool pf = (t2 < NT);
        const int bf2 = t2 % 3;
#pragma unroll
        for (int kk = 0; kk < 2; ++kk) {
            // ---- phase 2kk: 6 ds_reads + 2 gloads, MFMA mf={0,1} ----
            short8 aa[2], bb[4];
            aa[0] = LDA(Ac, 0, kk); aa[1] = LDA(Ac, 1, kk);
            bb[0] = LDB(Bc, 0, kk); bb[1] = LDB(Bc, 1, kk);
            bb[2] = LDB(Bc, 2, kk); bb[3] = LDB(Bc, 3, kk);
            if (pf) { if (kk == 0) stageA(bf2, t2); else stageB(bf2, t2, 2); }
            barrier_nodrain();
            asm volatile("s_waitcnt lgkmcnt(0)" ::: "memory");
            __builtin_amdgcn_sched_barrier(0);
            __builtin_amdgcn_s_setprio(1);
#pragma unroll
            for (int m = 0; m < 2; ++m)
#pragma unroll
                for (int n = 0; n < 4; ++n)
                    acc[m][n] = __builtin_amdgcn_mfma_f32_16x16x32_bf16(
                        aa[m], bb[n], acc[m][n], 0, 0, 0);
            __builtin_amdgcn_s_setprio(0);
            barrier_nodrain();
            // ---- phase 2kk+1: 2 ds_reads + (kk==0: 2 gloads), MFMA mf={2,3} ----
            short8 a2[2];
            a2[0] = LDA(Ac, 2, kk); a2[1] = LDA(Ac, 3, kk);
            if (pf && kk == 0) stageB(bf2, t2, 0);
            barrier_nodrain();
            asm volatile("s_waitcnt lgkmcnt(0)" ::: "memory");
            __builtin_amdgcn_sched_barrier(0);
            __builtin_amdgcn_s_setprio(1);
#pragma unroll
            for (int m = 0; m < 2; ++m)
#pragma unroll
                for (int n = 0; n < 4; ++n)
                    acc[m + 2][n] = __builtin_amdgcn_mfma_f32_16x16x32_bf16(
                        a2[m], bb[n], acc[m + 2][n], 0, 0, 0);
            __builtin_amdgcn_s_setprio(0);
            barrier_nodrain();
        }
    }

    if constexpr (ROPE) {
        if (n0 < 2048) {   // block-uniform: Q/K columns only
#pragma unroll
            for (int mf = 0; mf < 4; ++mf)
#pragma unroll
                for (int nf = 0; nf < 4; ++nf) {
                    const int ii = (nf * 16 + l16) >> 1;
                    const float sgn = (l16 & 1) ? 1.0f : -1.0f;
#pragma unroll
                    for (int rr = 0; rr < 4; ++rr) {
                        int row = m0 + wm * 64 + mf * 16 + lq * 4 + rr;
                        float v = acc[mf][nf][rr];
                        float p = __shfl_xor(v, 1);
                        float2 cs = tab[(row & (T_ - 1)) * 32 + ii];
                        acc[mf][nf][rr] = v * cs.x + sgn * (p * cs.y);
                    }
                }
        }
    }
#pragma unroll
    for (int mf = 0; mf < 4; ++mf)
#pragma unroll
        for (int nf = 0; nf < 4; ++nf)
#pragma unroll
            for (int rr = 0; rr < 4; ++rr) {
                int row = m0 + wm * 64 + mf * 16 + lq * 4 + rr;
                int col = n0 + wn * 64 + nf * 16 + l16;
                if constexpr (CF32)
                    ((float*)Cp)[(size_t)row * N + col] = acc[mf][nf][rr];
                else
                    ((short*)Cp)[(size_t)row * N + col] = f2b(acc[mf][nf][rr]);
            }
}

// V region of qkv -> vT[(b*16+h)*64 + d][t]  (per-(b,h) 64 x 2048, bf16)
__global__ __launch_bounds__(256) void transpose_v(const short* __restrict__ qkv,
                                                   short* __restrict__ vT) {
    const int blk = blockIdx.x;
    const int bh = blk >> 5, tt = blk & 31;
    const int b = bh >> 4, h = bh & 15;
    const int t0 = tt * 64;
    const int tid = threadIdx.x;
    __shared__ int tile[64][65];
#pragma unroll
    for (int p = 0; p < 2; ++p) {
        int c = p * 256 + tid;
        int t = c >> 3, d0 = (c & 7) * 8;
        short8 v = *(const short8*)(qkv + (size_t)(b * T_ + t0 + t) * NQKV + 2 * C_ + h * 64 + d0);
#pragma unroll
        for (int u = 0; u < 8; ++u) tile[t][d0 + u] = v[u];
    }
    __syncthreads();
#pragma unroll
    for (int p = 0; p < 2; ++p) {
        int c = p * 256 + tid;
        int d = c >> 3, tq0 = (c & 7) * 8;
        short8 s;
#pragma unroll
        for (int u = 0; u < 8; ++u) s[u] = (short)tile[tq0 + u][d];
        *(short8*)(vT + (size_t)(bh * 64 + d) * 2048 + t0 + tq0) = s;
    }
}

// MFMA flash attention: block = (b,h,128 q rows), 4 waves x 2 row-groups.
// Base-2 online softmax via raw v_exp_f32, defer-max THR=8, packed b64 P staging.
__global__ __launch_bounds__(256) void attn_mfma(const short* __restrict__ qkv,
                                                 const short* __restrict__ vT,
                                                 short* __restrict__ att) {
    const int blk = blockIdx.x;
    const int bh = blk & 63;               // all heads of a qt dispatch together
    const int qt = 15 - (blk >> 6);        // heavy q-tiles first
    const int b = bh >> 4, h = bh & 15;
    const int q0 = qt * 128;
    const int tid = threadIdx.x;
    const int w = tid >> 6, l = tid & 63;
    const int l16 = l & 15, lq = l >> 4;
    const int e = l16 & 7;                 // row-XOR term for fragment reads

    __shared__ short Ks[2][64 * 64];
    __shared__ short Vs[2][64 * 64];
    __shared__ short Ps[4][16 * 64];

    short8 qf[2][2];
#pragma unroll
    for (int rg = 0; rg < 2; ++rg) {
        const size_t qrow = (size_t)((b * T_) + q0 + rg * 64 + w * 16 + l16) * NQKV + h * 64;
#pragma unroll
        for (int kk = 0; kk < 2; ++kk) {
            short8 raw = *(const short8*)(qkv + qrow + kk * 32 + lq * 8);
            short8 s;
#pragma unroll
            for (int j = 0; j < 8; ++j) s[j] = f2b(0.18033688011112042f * b2f(raw[j])); // 0.125*log2e
            qf[rg][kk] = s;
        }
    }
    f32x4 acc[2][4];
#pragma unroll
    for (int rg = 0; rg < 2; ++rg)
#pragma unroll
        for (int dt = 0; dt < 4; ++dt) acc[rg][dt] = fz4();
    float m_s[2] = {-1e30f, -1e30f}, l_s[2] = {0.f, 0.f};

    const int nt = 2 * qt + 2;
    auto stage = [&](int bf, int t) {   // 4 gload_lds per thread
        const int k0 = t * 64;
        const size_t kbase = (size_t)((b * T_) + k0) * NQKV + C_ + h * 64;
        const size_t vbase = (size_t)(bh * 64) * 2048 + k0;
#pragma unroll
        for (int p = 0; p < 2; ++p) {
            int c = p * 256 + tid;
            int r = c >> 3;
            int cg = (c & 7) ^ (r & 7);
            load_lds16(qkv + kbase + (size_t)r * NQKV + cg * 8,
                       &Ks[bf][(p * 256 + (tid & ~63)) * 8]);
            load_lds16(vT + vbase + (size_t)r * 2048 + cg * 8,
                       &Vs[bf][(p * 256 + (tid & ~63)) * 8]);
        }
    };

    stage(0, 0);
    for (int t = 0; t < nt; ++t) {
        const int k0 = t * 64;
        if (t + 1 < nt) {
            stage((t + 1) & 1, t + 1);
            asm volatile("s_waitcnt vmcnt(4)" ::: "memory");
        } else {
            asm volatile("s_waitcnt vmcnt(0)" ::: "memory");
        }
        barrier_nodrain();
        const short* Kc = Ks[t & 1];
        const short* Vc = Vs[t & 1];
#pragma unroll
        for (int rg = 0; rg < 2; ++rg) {
            if (rg == 0 && t == nt - 1) continue;   // block-uniform skip
            const int qg = q0 + rg * 64 + w * 16 + l16;
            f32x4 sc[4];
#pragma unroll
            for (int ct = 0; ct < 4; ++ct) sc[ct] = fz4();
            __builtin_amdgcn_s_setprio(1);
#pragma unroll
            for (int kk = 0; kk < 2; ++kk)
#pragma unroll
                for (int ct = 0; ct < 4; ++ct) {
                    short8 ak = *(const short8*)&Kc[(ct * 16 + l16) * 64 + (((kk * 4 + lq) ^ e) * 8)];
                    sc[ct] = __builtin_amdgcn_mfma_f32_16x16x32_bf16(ak, qf[rg][kk], sc[ct], 0, 0, 0);
                }
            __builtin_amdgcn_s_setprio(0);
            if (k0 + 63 > q0 + rg * 64 + w * 16) {
#pragma unroll
                for (int ct = 0; ct < 4; ++ct)
#pragma unroll
                    for (int r = 0; r < 4; ++r)
                        if (k0 + ct * 16 + lq * 4 + r > qg) sc[ct][r] = -1e30f;
            }
            // row max (base-2 units); lanes sharing l16 hold one q-row
            float mx = -1e30f;
#pragma unroll
            for (int ct = 0; ct < 4; ++ct)
#pragma unroll
                for (int r = 0; r < 4; ++r) mx = fmaxf(mx, sc[ct][r]);
            mx = fmaxf(mx, __shfl_xor(mx, 16));
            mx = fmaxf(mx, __shfl_xor(mx, 32));
            // defer-max: skip rescale when max growth <= 8 (P bounded by 2^8)
            const bool skip = __all(mx <= m_s[rg] + 8.0f);
            const float mn = skip ? m_s[rg] : fmaxf(m_s[rg], mx);
            float s0 = 0.f;
#pragma unroll
            for (int ct = 0; ct < 4; ++ct) {
                short4v pv;
#pragma unroll
                for (int r = 0; r < 4; ++r) {
                    float p = exp2_raw(sc[ct][r] - mn);
                    pv[r] = f2b(p);
                    s0 += p;
                }
                *(short4v*)&Ps[w][l16 * 64 + (((ct * 2 + (lq >> 1)) ^ e) * 8) + (lq & 1) * 4] = pv;
            }
            s0 += __shfl_xor(s0, 16);
            s0 += __shfl_xor(s0, 32);
            if (skip) {
                l_s[rg] += s0;
            } else {
                float al = exp2_raw(m_s[rg] - mn);
                m_s[rg] = mn;
                l_s[rg] = l_s[rg] * al + s0;
                float albc[4];
#pragma unroll
                for (int r = 0; r < 4; ++r) albc[r] = __shfl(al, lq * 4 + r);
#pragma unroll
                for (int dt = 0; dt < 4; ++dt) {
                    f32x4 a4 = acc[rg][dt];
                    a4[0] *= albc[0]; a4[1] *= albc[1]; a4[2] *= albc[2]; a4[3] *= albc[3];
                    acc[rg][dt] = a4;
                }
            }
            __builtin_amdgcn_s_setprio(1);
#pragma unroll
            for (int kk = 0; kk < 2; ++kk) {
                short8 pa = *(const short8*)&Ps[w][l16 * 64 + (((kk * 4 + lq) ^ e) * 8)];
#pragma unroll
                for (int dt = 0; dt < 4; ++dt) {
                    short8 bv = *(const short8*)&Vc[(dt * 16 + l16) * 64 + (((kk * 4 + lq) ^ e) * 8)];
                    acc[rg][dt] = __builtin_amdgcn_mfma_f32_16x16x32_bf16(pa, bv, acc[rg][dt], 0, 0, 0);
                }
            }
            __builtin_amdgcn_s_setprio(0);
        }
        barrier_nodrain();
    }
#pragma unroll
    for (int rg = 0; rg < 2; ++rg) {
        float lbc[4];
#pragma unroll
        for (int r = 0; r < 4; ++r) lbc[r] = __shfl(l_s[rg], lq * 4 + r);
#pragma unroll
        for (int r = 0; r < 4; ++r) {
            float inv = 1.0f / lbc[r];
            size_t ob = (size_t)((b * T_) + q0 + rg * 64 + w * 16 + lq * 4 + r) * C_ + h * 64 + l16;
#pragma unroll
            for (int dt = 0; dt < 4; ++dt)
                att[ob + dt * 16] = f2b(acc[rg][dt][r] * inv);
        }
    }
}

extern "C" void kernel_launch(void* const* d_in, const int* in_sizes, int n_in,
                              void* d_out, int out_size, void* d_ws, size_t ws_size,
                              hipStream_t stream) {
    const float* x = (const float*)d_in[0];
    const float* Wqkv = (const float*)d_in[1];
    const float* Wproj = (const float*)d_in[2];
    char* ws = (char*)d_ws;

    short* qkv = (short*)ws;                                     // [0, 48MB)
    short* att = (short*)(ws + (size_t)BT_ * NQKV * 2);          // [48MB, 64MB)
    short* wqb = att;                                            // 6MB, dead before att written
    float2* tab = (float2*)(ws + (size_t)BT_ * NQKV * 2 + (size_t)3 * C_ * C_ * 2); // 512KB
    short* wpb = qkv;                                            // 2MB, qkv dead by then
    short* vT  = (short*)d_out;                                  // d_out[0,16MB): V^T scratch
    short* xb  = (short*)((char*)d_out + ((size_t)BT_ * C_ * 2)); // d_out[16,32MB): x bf16

    // 1) rope table + x,Wqkv -> bf16
    rope_table<<<256, 256, 0, stream>>>(tab);
    cvt_kernel<<<(BT_ * C_) / 2048, 256, 0, stream>>>(x, xb, BT_ * C_);
    cvt_kernel<<<(3 * C_ * C_) / 2048, 256, 0, stream>>>(Wqkv, wqb, 3 * C_ * C_);
    // 2) qkv = xb @ Wqkv^T with fused RoPE (bf16 out)
    dim3 g1(BT_ / 128, NQKV / 256);
    gemm_pipe<0, 1><<<g1, 512, 0, stream>>>(xb, wqb, (void*)qkv, BT_, NQKV, C_, tab);
    // 3) V -> vT (per-(b,h) transpose)
    transpose_v<<<64 * 32, 256, 0, stream>>>(qkv, vT);
    // 4) attention
    attn_mfma<<<B_ * H_ * (T_ / 128), 256, 0, stream>>>(qkv, vT, att);
    // 5) Wproj -> bf16
    cvt_kernel<<<(C_ * C_) / 2048, 256, 0, stream>>>(Wproj, wpb, C_ * C_);
    // 6) out = att @ Wproj^T (fp32 out; overwrites vT/xb scratch)
    dim3 g2(BT_ / 128, C_ / 256);
    gemm_pipe<1, 0><<<g2, 512, 0, stream>>>(att, wpb, d_out, BT_, C_, C_, tab);
}

// Round 14
// 193.287 us; speedup vs baseline: 1.0945x; 1.0945x over previous
//
#include <hip/hip_runtime.h>
#include <hip/hip_bf16.h>

#define B_   4
#define T_   2048
#define C_   1024
#define H_   16
#define BT_  (B_ * T_)      // 8192
#define NQKV (3 * C_)       // 3072

typedef __attribute__((ext_vector_type(8))) short short8;
typedef __attribute__((ext_vector_type(4))) short short4v;
typedef __attribute__((ext_vector_type(4))) float f32x4;

__device__ inline float b2f(short u) {
    unsigned int x = ((unsigned int)(unsigned short)u) << 16;
    float f;
    __builtin_memcpy(&f, &x, 4);
    return f;
}
__device__ inline short f2b(float f) {
    __hip_bfloat16 h = __float2bfloat16(f);
    unsigned short u;
    __builtin_memcpy(&u, &h, 2);
    return (short)u;
}
__device__ inline f32x4 fz4() { f32x4 z; z[0] = z[1] = z[2] = z[3] = 0.f; return z; }
__device__ inline float exp2_raw(float x) {   // bare v_exp_f32 (=2^x), no libm fixup
    float r;
    asm("v_exp_f32 %0, %1" : "=v"(r) : "v"(x));
    return r;
}

__device__ inline void load_lds16(const void* g, void* l) {
    __builtin_amdgcn_global_load_lds((const __attribute__((address_space(1))) unsigned int*)g,
                                     (__attribute__((address_space(3))) unsigned int*)l,
                                     16, 0, 0);
}
__device__ inline void barrier_nodrain() {
    __builtin_amdgcn_sched_barrier(0);
    __builtin_amdgcn_s_barrier();
    __builtin_amdgcn_sched_barrier(0);
}

// fp32 -> bf16 bulk convert (n multiple of 2048)
__global__ __launch_bounds__(256) void cvt_kernel(const float* __restrict__ in,
                                                  short* __restrict__ out, int n) {
    int i = (blockIdx.x * 256 + threadIdx.x) * 8;
    if (i >= n) return;
    float4 a = *(const float4*)(in + i);
    float4 b = *(const float4*)(in + i + 4);
    short8 s;
    s[0] = f2b(a.x); s[1] = f2b(a.y); s[2] = f2b(a.z); s[3] = f2b(a.w);
    s[4] = f2b(b.x); s[5] = f2b(b.y); s[6] = f2b(b.z); s[7] = f2b(b.w);
    *(short8*)(out + i) = s;
}

// cos/sin table: tab[t*32+i] = (cos, sin) of t * 10000^(-i/32), t<2048, i<32
__global__ __launch_bounds__(256) void rope_table(float2* __restrict__ tab) {
    int idx = blockIdx.x * 256 + threadIdx.x;   // 65536
    int t = idx >> 5, i = idx & 31;
    float inv = exp2f(-(float)i * 0.41524101186092029f);
    float ang = (float)t * inv;
    float s, c;
    sincosf(ang, &s, &c);
    tab[idx] = make_float2(c, s);
}

// C[m][n] = sum_k A[m][k]*Bw[n][k]; A,Bw bf16 [.][K]. 128x256 block, BK=64,
// 8 waves (2Mx4N, 64x64 wave-tile). RING-3 LDS, prefetch distance 2,
// ONE barrier per K-step, counted vmcnt(6). (R12 measured-best form.)
template <int CF32, int ROPE>
__global__ __launch_bounds__(512) void gemm_pipe(const short* __restrict__ Ab,
                                                 const short* __restrict__ Bw,
                                                 void* __restrict__ Cp,
                                                 int M, int N, int K,
                                                 const float2* __restrict__ tab) {
    __shared__ short As[3][128 * 64];
    __shared__ short Bs[3][256 * 64];
    const int tid = threadIdx.x;
    const int l16 = tid & 15, lq = (tid & 63) >> 4;
    const int wid = tid >> 6;          // 0..7
    const int wm = wid >> 2, wn = wid & 3;   // 2M x 4N wave grid
    const int m0 = blockIdx.x * 128, n0 = blockIdx.y * 256;
    const int NT = K >> 6;

    f32x4 acc[4][4];
#pragma unroll
    for (int i = 0; i < 4; ++i)
#pragma unroll
        for (int j = 0; j < 4; ++j) acc[i][j] = fz4();

    auto stage = [&](int bf, int t) {   // 6 gload_lds per thread
        const int k0 = t * 64;
#pragma unroll
        for (int p = 0; p < 2; ++p) {
            int c = p * 512 + tid;
            int r = c >> 3, cs = (c & 7) ^ (r & 7);
            load_lds16(Ab + (size_t)(m0 + r) * K + k0 + cs * 8,
                       &As[bf][(p * 512 + (tid & ~63)) * 8]);
        }
#pragma unroll
        for (int p = 0; p < 4; ++p) {
            int c = p * 512 + tid;
            int r = c >> 3, cs = (c & 7) ^ (r & 7);
            load_lds16(Bw + (size_t)(n0 + r) * K + k0 + cs * 8,
                       &Bs[bf][(p * 512 + (tid & ~63)) * 8]);
        }
    };

    stage(0, 0);
    if (NT > 1) stage(1, 1);
    for (int t = 0; t < NT; ++t) {
        if (t + 1 < NT) {
            asm volatile("s_waitcnt vmcnt(6)" ::: "memory");
        } else {
            asm volatile("s_waitcnt vmcnt(0)" ::: "memory");
        }
        barrier_nodrain();               // tile t resident; iter t-1 reads done
        if (t + 2 < NT) stage((t + 2) % 3, t + 2);
        const short* Ac = As[t % 3];
        const short* Bc = Bs[t % 3];
#pragma unroll
        for (int kk = 0; kk < 2; ++kk) {
            short8 af[4], bfr[4];
#pragma unroll
            for (int mf = 0; mf < 4; ++mf) {
                int row = wm * 64 + mf * 16 + l16;
                af[mf] = *(const short8*)&Ac[row * 64 + (((kk * 4 + lq) ^ (row & 7)) * 8)];
            }
#pragma unroll
            for (int nf = 0; nf < 4; ++nf) {
                int row = wn * 64 + nf * 16 + l16;
                bfr[nf] = *(const short8*)&Bc[row * 64 + (((kk * 4 + lq) ^ (row & 7)) * 8)];
            }
            __builtin_amdgcn_s_setprio(1);
#pragma unroll
            for (int mf = 0; mf < 4; ++mf)
#pragma unroll
                for (int nf = 0; nf < 4; ++nf)
                    acc[mf][nf] = __builtin_amdgcn_mfma_f32_16x16x32_bf16(
                        af[mf], bfr[nf], acc[mf][nf], 0, 0, 0);
            __builtin_amdgcn_s_setprio(0);
        }
    }

    if constexpr (ROPE) {
        if (n0 < 2048) {   // block-uniform: Q/K columns only
#pragma unroll
            for (int mf = 0; mf < 4; ++mf)
#pragma unroll
                for (int nf = 0; nf < 4; ++nf) {
                    const int ii = (nf * 16 + l16) >> 1;
                    const float sgn = (l16 & 1) ? 1.0f : -1.0f;
#pragma unroll
                    for (int rr = 0; rr < 4; ++rr) {
                        int row = m0 + wm * 64 + mf * 16 + lq * 4 + rr;
                        float v = acc[mf][nf][rr];
                        float p = __shfl_xor(v, 1);
                        float2 cs = tab[(row & (T_ - 1)) * 32 + ii];
                        acc[mf][nf][rr] = v * cs.x + sgn * (p * cs.y);
                    }
                }
        }
    }
#pragma unroll
    for (int mf = 0; mf < 4; ++mf)
#pragma unroll
        for (int nf = 0; nf < 4; ++nf)
#pragma unroll
            for (int rr = 0; rr < 4; ++rr) {
                int row = m0 + wm * 64 + mf * 16 + lq * 4 + rr;
                int col = n0 + wn * 64 + nf * 16 + l16;
                if constexpr (CF32)
                    ((float*)Cp)[(size_t)row * N + col] = acc[mf][nf][rr];
                else
                    ((short*)Cp)[(size_t)row * N + col] = f2b(acc[mf][nf][rr]);
            }
}

// V region of qkv -> vT[(b*16+h)*64 + d][t]  (per-(b,h) 64 x 2048, bf16)
__global__ __launch_bounds__(256) void transpose_v(const short* __restrict__ qkv,
                                                   short* __restrict__ vT) {
    const int blk = blockIdx.x;
    const int bh = blk >> 5, tt = blk & 31;
    const int b = bh >> 4, h = bh & 15;
    const int t0 = tt * 64;
    const int tid = threadIdx.x;
    __shared__ int tile[64][65];
#pragma unroll
    for (int p = 0; p < 2; ++p) {
        int c = p * 256 + tid;
        int t = c >> 3, d0 = (c & 7) * 8;
        short8 v = *(const short8*)(qkv + (size_t)(b * T_ + t0 + t) * NQKV + 2 * C_ + h * 64 + d0);
#pragma unroll
        for (int u = 0; u < 8; ++u) tile[t][d0 + u] = v[u];
    }
    __syncthreads();
#pragma unroll
    for (int p = 0; p < 2; ++p) {
        int c = p * 256 + tid;
        int d = c >> 3, tq0 = (c & 7) * 8;
        short8 s;
#pragma unroll
        for (int u = 0; u < 8; ++u) s[u] = (short)tile[tq0 + u][d];
        *(short8*)(vT + (size_t)(bh * 64 + d) * 2048 + t0 + tq0) = s;
    }
}

// MFMA flash attention: block = (b,h,128 q rows), 8 waves x 16 rows (no rg loop).
// Base-2 online softmax via raw v_exp_f32, defer-max THR=8, packed b64 P staging.
__global__ __launch_bounds__(512) void attn_mfma(const short* __restrict__ qkv,
                                                 const short* __restrict__ vT,
                                                 short* __restrict__ att) {
    const int blk = blockIdx.x;
    const int bh = blk & 63;               // all heads of a qt dispatch together
    const int qt = 15 - (blk >> 6);        // heavy q-tiles first
    const int b = bh >> 4, h = bh & 15;
    const int q0 = qt * 128;
    const int tid = threadIdx.x;
    const int w = tid >> 6, l = tid & 63;  // w: 0..7, 16 q-rows per wave
    const int l16 = l & 15, lq = l >> 4;
    const int e = l16 & 7;                 // row-XOR term for fragment reads

    __shared__ short Ks[2][64 * 64];
    __shared__ short Vs[2][64 * 64];
    __shared__ short Ps[8][16 * 64];

    short8 qf[2];
    {
        const size_t qrow = (size_t)((b * T_) + q0 + w * 16 + l16) * NQKV + h * 64;
#pragma unroll
        for (int kk = 0; kk < 2; ++kk) {
            short8 raw = *(const short8*)(qkv + qrow + kk * 32 + lq * 8);
            short8 s;
#pragma unroll
            for (int j = 0; j < 8; ++j) s[j] = f2b(0.18033688011112042f * b2f(raw[j])); // 0.125*log2e
            qf[kk] = s;
        }
    }
    f32x4 acc[4];
#pragma unroll
    for (int dt = 0; dt < 4; ++dt) acc[dt] = fz4();
    float m_s = -1e30f, l_s = 0.f;

    const int nt = 2 * qt + 2;
    const int qg_max = q0 + w * 16 + 15;   // wave's last q row
    auto stage = [&](int bf, int t) {      // 2 gload_lds per thread (512 threads)
        const int k0 = t * 64;
        const size_t kbase = (size_t)((b * T_) + k0) * NQKV + C_ + h * 64;
        const size_t vbase = (size_t)(bh * 64) * 2048 + k0;
        int r = tid >> 3;
        int cg = (tid & 7) ^ (r & 7);
        load_lds16(qkv + kbase + (size_t)r * NQKV + cg * 8, &Ks[bf][(tid & ~63) * 8]);
        load_lds16(vT + vbase + (size_t)r * 2048 + cg * 8, &Vs[bf][(tid & ~63) * 8]);
    };

    stage(0, 0);
    for (int t = 0; t < nt; ++t) {
        const int k0 = t * 64;
        if (t + 1 < nt) {
            stage((t + 1) & 1, t + 1);
            asm volatile("s_waitcnt vmcnt(2)" ::: "memory");
        } else {
            asm volatile("s_waitcnt vmcnt(0)" ::: "memory");
        }
        barrier_nodrain();
        const short* Kc = Ks[t & 1];
        const short* Vc = Vs[t & 1];
        if (k0 <= qg_max) {                // wave-uniform: tile has unmasked cols
            const int qg = q0 + w * 16 + l16;
            f32x4 sc[4];
#pragma unroll
            for (int ct = 0; ct < 4; ++ct) sc[ct] = fz4();
            __builtin_amdgcn_s_setprio(1);
#pragma unroll
            for (int kk = 0; kk < 2; ++kk)
#pragma unroll
                for (int ct = 0; ct < 4; ++ct) {
                    short8 ak = *(const short8*)&Kc[(ct * 16 + l16) * 64 + (((kk * 4 + lq) ^ e) * 8)];
                    sc[ct] = __builtin_amdgcn_mfma_f32_16x16x32_bf16(ak, qf[kk], sc[ct], 0, 0, 0);
                }
            __builtin_amdgcn_s_setprio(0);
            if (k0 + 63 > q0 + w * 16) {
#pragma unroll
                for (int ct = 0; ct < 4; ++ct)
#pragma unroll
                    for (int r = 0; r < 4; ++r)
                        if (k0 + ct * 16 + lq * 4 + r > qg) sc[ct][r] = -1e30f;
            }
            // row max (base-2 units); lane holds q-row l16
            float mx = -1e30f;
#pragma unroll
            for (int ct = 0; ct < 4; ++ct)
#pragma unroll
                for (int r = 0; r < 4; ++r) mx = fmaxf(mx, sc[ct][r]);
            mx = fmaxf(mx, __shfl_xor(mx, 16));
            mx = fmaxf(mx, __shfl_xor(mx, 32));
            const bool skip = __all(mx <= m_s + 8.0f);
            const float mn = skip ? m_s : fmaxf(m_s, mx);
            float s0 = 0.f;
#pragma unroll
            for (int ct = 0; ct < 4; ++ct) {
                short4v pv;
#pragma unroll
                for (int r = 0; r < 4; ++r) {
                    float p = exp2_raw(sc[ct][r] - mn);
                    pv[r] = f2b(p);
                    s0 += p;
                }
                *(short4v*)&Ps[w][l16 * 64 + (((ct * 2 + (lq >> 1)) ^ e) * 8) + (lq & 1) * 4] = pv;
            }
            s0 += __shfl_xor(s0, 16);
            s0 += __shfl_xor(s0, 32);
            if (skip) {
                l_s += s0;
            } else {
                float al = exp2_raw(m_s - mn);
                m_s = mn;
                l_s = l_s * al + s0;
                float albc[4];
#pragma unroll
                for (int r = 0; r < 4; ++r) albc[r] = __shfl(al, lq * 4 + r);
#pragma unroll
                for (int dt = 0; dt < 4; ++dt) {
                    f32x4 a4 = acc[dt];
                    a4[0] *= albc[0]; a4[1] *= albc[1]; a4[2] *= albc[2]; a4[3] *= albc[3];
                    acc[dt] = a4;
                }
            }
            __builtin_amdgcn_s_setprio(1);
#pragma unroll
            for (int kk = 0; kk < 2; ++kk) {
                short8 pa = *(const short8*)&Ps[w][l16 * 64 + (((kk * 4 + lq) ^ e) * 8)];
#pragma unroll
                for (int dt = 0; dt < 4; ++dt) {
                    short8 bv = *(const short8*)&Vc[(dt * 16 + l16) * 64 + (((kk * 4 + lq) ^ e) * 8)];
                    acc[dt] = __builtin_amdgcn_mfma_f32_16x16x32_bf16(pa, bv, acc[dt], 0, 0, 0);
                }
            }
            __builtin_amdgcn_s_setprio(0);
        }
        barrier_nodrain();
    }
    {
        float lbc[4];
#pragma unroll
        for (int r = 0; r < 4; ++r) lbc[r] = __shfl(l_s, lq * 4 + r);
#pragma unroll
        for (int r = 0; r < 4; ++r) {
            float inv = 1.0f / lbc[r];
            size_t ob = (size_t)((b * T_) + q0 + w * 16 + lq * 4 + r) * C_ + h * 64 + l16;
#pragma unroll
            for (int dt = 0; dt < 4; ++dt)
                att[ob + dt * 16] = f2b(acc[dt][r] * inv);
        }
    }
}

extern "C" void kernel_launch(void* const* d_in, const int* in_sizes, int n_in,
                              void* d_out, int out_size, void* d_ws, size_t ws_size,
                              hipStream_t stream) {
    const float* x = (const float*)d_in[0];
    const float* Wqkv = (const float*)d_in[1];
    const float* Wproj = (const float*)d_in[2];
    char* ws = (char*)d_ws;

    short* qkv = (short*)ws;                                     // [0, 48MB)
    short* att = (short*)(ws + (size_t)BT_ * NQKV * 2);          // [48MB, 64MB)
    short* wqb = att;                                            // 6MB, dead before att written
    float2* tab = (float2*)(ws + (size_t)BT_ * NQKV * 2 + (size_t)3 * C_ * C_ * 2); // 512KB
    short* wpb = qkv;                                            // 2MB, qkv dead by then
    short* vT  = (short*)d_out;                                  // d_out[0,16MB): V^T scratch
    short* xb  = (short*)((char*)d_out + ((size_t)BT_ * C_ * 2)); // d_out[16,32MB): x bf16

    // 1) rope table + x,Wqkv -> bf16
    rope_table<<<256, 256, 0, stream>>>(tab);
    cvt_kernel<<<(BT_ * C_) / 2048, 256, 0, stream>>>(x, xb, BT_ * C_);
    cvt_kernel<<<(3 * C_ * C_) / 2048, 256, 0, stream>>>(Wqkv, wqb, 3 * C_ * C_);
    // 2) qkv = xb @ Wqkv^T with fused RoPE (bf16 out)
    dim3 g1(BT_ / 128, NQKV / 256);
    gemm_pipe<0, 1><<<g1, 512, 0, stream>>>(xb, wqb, (void*)qkv, BT_, NQKV, C_, tab);
    // 3) V -> vT (per-(b,h) transpose)
    transpose_v<<<64 * 32, 256, 0, stream>>>(qkv, vT);
    // 4) attention
    attn_mfma<<<B_ * H_ * (T_ / 128), 512, 0, stream>>>(qkv, vT, att);
    // 5) Wproj -> bf16
    cvt_kernel<<<(C_ * C_) / 2048, 256, 0, stream>>>(Wproj, wpb, C_ * C_);
    // 6) out = att @ Wproj^T (fp32 out; overwrites vT/xb scratch)
    dim3 g2(BT_ / 128, C_ / 256);
    gemm_pipe<1, 0><<<g2, 512, 0, stream>>>(att, wpb, d_out, BT_, C_, C_, tab);
}

// Round 15
// 179.135 us; speedup vs baseline: 1.1809x; 1.0790x over previous
//
#include <hip/hip_runtime.h>
#include <hip/hip_bf16.h>

#define B_   4
#define T_   2048
#define C_   1024
#define H_   16
#define BT_  (B_ * T_)      // 8192
#define NQKV (3 * C_)       // 3072

typedef __attribute__((ext_vector_type(8))) short short8;
typedef __attribute__((ext_vector_type(4))) short short4v;
typedef __attribute__((ext_vector_type(4))) float f32x4;

__device__ inline float b2f(short u) {
    unsigned int x = ((unsigned int)(unsigned short)u) << 16;
    float f;
    __builtin_memcpy(&f, &x, 4);
    return f;
}
__device__ inline short f2b(float f) {
    __hip_bfloat16 h = __float2bfloat16(f);
    unsigned short u;
    __builtin_memcpy(&u, &h, 2);
    return (short)u;
}
__device__ inline f32x4 fz4() { f32x4 z; z[0] = z[1] = z[2] = z[3] = 0.f; return z; }
__device__ inline float exp2_raw(float x) {   // bare v_exp_f32 (=2^x), no libm fixup
    float r;
    asm("v_exp_f32 %0, %1" : "=v"(r) : "v"(x));
    return r;
}

__device__ inline void load_lds16(const void* g, void* l) {
    __builtin_amdgcn_global_load_lds((const __attribute__((address_space(1))) unsigned int*)g,
                                     (__attribute__((address_space(3))) unsigned int*)l,
                                     16, 0, 0);
}
__device__ inline void barrier_nodrain() {
    __builtin_amdgcn_sched_barrier(0);
    __builtin_amdgcn_s_barrier();
    __builtin_amdgcn_sched_barrier(0);
}

__device__ inline void cvt8(const float* in, short* out, int i) {
    float4 a = *(const float4*)(in + i);
    float4 b = *(const float4*)(in + i + 4);
    short8 s;
    s[0] = f2b(a.x); s[1] = f2b(a.y); s[2] = f2b(a.z); s[3] = f2b(a.w);
    s[4] = f2b(b.x); s[5] = f2b(b.y); s[6] = f2b(b.z); s[7] = f2b(b.w);
    *(short8*)(out + i) = s;
}

// fp32 -> bf16 bulk convert (n multiple of 2048)
__global__ __launch_bounds__(256) void cvt_kernel(const float* __restrict__ in,
                                                  short* __restrict__ out, int n) {
    int i = (blockIdx.x * 256 + threadIdx.x) * 8;
    if (i >= n) return;
    cvt8(in, out, i);
}

// Fused prep: x->bf16 (4096 blocks), Wqkv->bf16 (1536 blocks), rope table (256 blocks)
__global__ __launch_bounds__(256) void prep_kernel(const float* __restrict__ x,
                                                   const float* __restrict__ Wqkv,
                                                   short* __restrict__ xb,
                                                   short* __restrict__ wqb,
                                                   float2* __restrict__ tab) {
    const int XB = (BT_ * C_) / 2048;        // 4096
    const int WB = (3 * C_ * C_) / 2048;     // 1536
    int bid = blockIdx.x;
    if (bid < XB) {
        cvt8(x, xb, (bid * 256 + threadIdx.x) * 8);
    } else if (bid < XB + WB) {
        cvt8(Wqkv, wqb, ((bid - XB) * 256 + threadIdx.x) * 8);
    } else {
        int idx = (bid - XB - WB) * 256 + threadIdx.x;   // 65536
        int t = idx >> 5, i = idx & 31;
        float inv = exp2f(-(float)i * 0.41524101186092029f);
        float ang = (float)t * inv;
        float s, c;
        sincosf(ang, &s, &c);
        tab[idx] = make_float2(c, s);
    }
}

// C[m][n] = sum_k A[m][k]*Bw[n][k]; A,Bw bf16 [.][K]. 128x256 block, BK=64,
// 8 waves (2Mx4N, 64x64 wave-tile). RING-3 LDS, prefetch distance 2,
// ONE barrier per K-step, counted vmcnt(6). (R12/R14 measured-best form.)
// TRANSV: blocks with n0>=2048 (V columns) write TRANSPOSED to vT via LDS
// restage instead of writing qkv (replaces the standalone transpose_v kernel).
template <int CF32, int ROPE, int TRANSV>
__global__ __launch_bounds__(512) void gemm_pipe(const short* __restrict__ Ab,
                                                 const short* __restrict__ Bw,
                                                 void* __restrict__ Cp,
                                                 int M, int N, int K,
                                                 const float2* __restrict__ tab,
                                                 short* __restrict__ vT) {
    __shared__ short As[3][128 * 64];
    __shared__ short Bs[3][256 * 64];
    const int tid = threadIdx.x;
    const int l16 = tid & 15, lq = (tid & 63) >> 4;
    const int wid = tid >> 6;          // 0..7
    const int wm = wid >> 2, wn = wid & 3;   // 2M x 4N wave grid
    const int m0 = blockIdx.x * 128, n0 = blockIdx.y * 256;
    const int NT = K >> 6;

    f32x4 acc[4][4];
#pragma unroll
    for (int i = 0; i < 4; ++i)
#pragma unroll
        for (int j = 0; j < 4; ++j) acc[i][j] = fz4();

    auto stage = [&](int bf, int t) {   // 6 gload_lds per thread
        const int k0 = t * 64;
#pragma unroll
        for (int p = 0; p < 2; ++p) {
            int c = p * 512 + tid;
            int r = c >> 3, cs = (c & 7) ^ (r & 7);
            load_lds16(Ab + (size_t)(m0 + r) * K + k0 + cs * 8,
                       &As[bf][(p * 512 + (tid & ~63)) * 8]);
        }
#pragma unroll
        for (int p = 0; p < 4; ++p) {
            int c = p * 512 + tid;
            int r = c >> 3, cs = (c & 7) ^ (r & 7);
            load_lds16(Bw + (size_t)(n0 + r) * K + k0 + cs * 8,
                       &Bs[bf][(p * 512 + (tid & ~63)) * 8]);
        }
    };

    stage(0, 0);
    if (NT > 1) stage(1, 1);
    for (int t = 0; t < NT; ++t) {
        if (t + 1 < NT) {
            asm volatile("s_waitcnt vmcnt(6)" ::: "memory");
        } else {
            asm volatile("s_waitcnt vmcnt(0)" ::: "memory");
        }
        barrier_nodrain();               // tile t resident; iter t-1 reads done
        if (t + 2 < NT) stage((t + 2) % 3, t + 2);
        const short* Ac = As[t % 3];
        const short* Bc = Bs[t % 3];
#pragma unroll
        for (int kk = 0; kk < 2; ++kk) {
            short8 af[4], bfr[4];
#pragma unroll
            for (int mf = 0; mf < 4; ++mf) {
                int row = wm * 64 + mf * 16 + l16;
                af[mf] = *(const short8*)&Ac[row * 64 + (((kk * 4 + lq) ^ (row & 7)) * 8)];
            }
#pragma unroll
            for (int nf = 0; nf < 4; ++nf) {
                int row = wn * 64 + nf * 16 + l16;
                bfr[nf] = *(const short8*)&Bc[row * 64 + (((kk * 4 + lq) ^ (row & 7)) * 8)];
            }
            __builtin_amdgcn_s_setprio(1);
#pragma unroll
            for (int mf = 0; mf < 4; ++mf)
#pragma unroll
                for (int nf = 0; nf < 4; ++nf)
                    acc[mf][nf] = __builtin_amdgcn_mfma_f32_16x16x32_bf16(
                        af[mf], bfr[nf], acc[mf][nf], 0, 0, 0);
            __builtin_amdgcn_s_setprio(0);
        }
    }

    if constexpr (TRANSV) {
        if (n0 >= 2048) {   // V columns: transposed write to vT via LDS restage
            short* Ld = (short*)Bs;      // 256 x 136 pad = 69.6KB, staging LDS is dead
            barrier_nodrain();           // all waves done reading As/Bs
#pragma unroll
            for (int mf = 0; mf < 4; ++mf)
#pragma unroll
                for (int nf = 0; nf < 4; ++nf) {
                    int c = wn * 64 + nf * 16 + l16;
                    int tt = wm * 64 + mf * 16 + lq * 4;
                    short4v pv;
#pragma unroll
                    for (int rr = 0; rr < 4; ++rr) pv[rr] = f2b(acc[mf][nf][rr]);
                    *(short4v*)&Ld[c * 136 + tt] = pv;
                }
            barrier_nodrain();
            const int bb = m0 >> 11;     // batch
            const int t0 = m0 & 2047;
#pragma unroll
            for (int p = 0; p < 8; ++p) {
                int q = p * 512 + tid;   // 4096 16B chunks
                int c = q >> 4, tq = q & 15;
                short8 s = *(const short8*)&Ld[c * 136 + tq * 8];
                int cg = (n0 - 2048) + c;           // h*64+d within batch
                *(short8*)(vT + (size_t)(bb * 1024 + cg) * 2048 + t0 + tq * 8) = s;
            }
            return;
        }
    }
    if constexpr (ROPE) {
        if (n0 < 2048) {   // block-uniform: Q/K columns only
#pragma unroll
            for (int mf = 0; mf < 4; ++mf)
#pragma unroll
                for (int nf = 0; nf < 4; ++nf) {
                    const int ii = (nf * 16 + l16) >> 1;
                    const float sgn = (l16 & 1) ? 1.0f : -1.0f;
#pragma unroll
                    for (int rr = 0; rr < 4; ++rr) {
                        int row = m0 + wm * 64 + mf * 16 + lq * 4 + rr;
                        float v = acc[mf][nf][rr];
                        float p = __shfl_xor(v, 1);
                        float2 cs = tab[(row & (T_ - 1)) * 32 + ii];
                        acc[mf][nf][rr] = v * cs.x + sgn * (p * cs.y);
                    }
                }
        }
    }
#pragma unroll
    for (int mf = 0; mf < 4; ++mf)
#pragma unroll
        for (int nf = 0; nf < 4; ++nf)
#pragma unroll
            for (int rr = 0; rr < 4; ++rr) {
                int row = m0 + wm * 64 + mf * 16 + lq * 4 + rr;
                int col = n0 + wn * 64 + nf * 16 + l16;
                if constexpr (CF32)
                    ((float*)Cp)[(size_t)row * N + col] = acc[mf][nf][rr];
                else
                    ((short*)Cp)[(size_t)row * N + col] = f2b(acc[mf][nf][rr]);
            }
}

// MFMA flash attention: block = (b,h,128 q rows), 8 waves x 16 rows.
// Base-2 online softmax via raw v_exp_f32, defer-max THR=8, packed b64 P staging.
__global__ __launch_bounds__(512) void attn_mfma(const short* __restrict__ qkv,
                                                 const short* __restrict__ vT,
                                                 short* __restrict__ att) {
    const int blk = blockIdx.x;
    const int bh = blk & 63;               // all heads of a qt dispatch together
    const int qt = 15 - (blk >> 6);        // heavy q-tiles first
    const int b = bh >> 4, h = bh & 15;
    const int q0 = qt * 128;
    const int tid = threadIdx.x;
    const int w = tid >> 6, l = tid & 63;  // w: 0..7, 16 q-rows per wave
    const int l16 = l & 15, lq = l >> 4;
    const int e = l16 & 7;                 // row-XOR term for fragment reads

    __shared__ short Ks[2][64 * 64];
    __shared__ short Vs[2][64 * 64];
    __shared__ short Ps[8][16 * 64];

    short8 qf[2];
    {
        const size_t qrow = (size_t)((b * T_) + q0 + w * 16 + l16) * NQKV + h * 64;
#pragma unroll
        for (int kk = 0; kk < 2; ++kk) {
            short8 raw = *(const short8*)(qkv + qrow + kk * 32 + lq * 8);
            short8 s;
#pragma unroll
            for (int j = 0; j < 8; ++j) s[j] = f2b(0.18033688011112042f * b2f(raw[j])); // 0.125*log2e
            qf[kk] = s;
        }
    }
    f32x4 acc[4];
#pragma unroll
    for (int dt = 0; dt < 4; ++dt) acc[dt] = fz4();
    float m_s = -1e30f, l_s = 0.f;

    const int nt = 2 * qt + 2;
    const int qg_max = q0 + w * 16 + 15;   // wave's last q row
    auto stage = [&](int bf, int t) {      // 2 gload_lds per thread (512 threads)
        const int k0 = t * 64;
        const size_t kbase = (size_t)((b * T_) + k0) * NQKV + C_ + h * 64;
        const size_t vbase = (size_t)(bh * 64) * 2048 + k0;
        int r = tid >> 3;
        int cg = (tid & 7) ^ (r & 7);
        load_lds16(qkv + kbase + (size_t)r * NQKV + cg * 8, &Ks[bf][(tid & ~63) * 8]);
        load_lds16(vT + vbase + (size_t)r * 2048 + cg * 8, &Vs[bf][(tid & ~63) * 8]);
    };

    stage(0, 0);
    for (int t = 0; t < nt; ++t) {
        const int k0 = t * 64;
        if (t + 1 < nt) {
            stage((t + 1) & 1, t + 1);
            asm volatile("s_waitcnt vmcnt(2)" ::: "memory");
        } else {
            asm volatile("s_waitcnt vmcnt(0)" ::: "memory");
        }
        barrier_nodrain();
        const short* Kc = Ks[t & 1];
        const short* Vc = Vs[t & 1];
        if (k0 <= qg_max) {                // wave-uniform: tile has unmasked cols
            const int qg = q0 + w * 16 + l16;
            f32x4 sc[4];
#pragma unroll
            for (int ct = 0; ct < 4; ++ct) sc[ct] = fz4();
            __builtin_amdgcn_s_setprio(1);
#pragma unroll
            for (int kk = 0; kk < 2; ++kk)
#pragma unroll
                for (int ct = 0; ct < 4; ++ct) {
                    short8 ak = *(const short8*)&Kc[(ct * 16 + l16) * 64 + (((kk * 4 + lq) ^ e) * 8)];
                    sc[ct] = __builtin_amdgcn_mfma_f32_16x16x32_bf16(ak, qf[kk], sc[ct], 0, 0, 0);
                }
            __builtin_amdgcn_s_setprio(0);
            if (k0 + 63 > q0 + w * 16) {
#pragma unroll
                for (int ct = 0; ct < 4; ++ct)
#pragma unroll
                    for (int r = 0; r < 4; ++r)
                        if (k0 + ct * 16 + lq * 4 + r > qg) sc[ct][r] = -1e30f;
            }
            float mx = -1e30f;
#pragma unroll
            for (int ct = 0; ct < 4; ++ct)
#pragma unroll
                for (int r = 0; r < 4; ++r) mx = fmaxf(mx, sc[ct][r]);
            mx = fmaxf(mx, __shfl_xor(mx, 16));
            mx = fmaxf(mx, __shfl_xor(mx, 32));
            const bool skip = __all(mx <= m_s + 8.0f);
            const float mn = skip ? m_s : fmaxf(m_s, mx);
            float s0 = 0.f;
#pragma unroll
            for (int ct = 0; ct < 4; ++ct) {
                short4v pv;
#pragma unroll
                for (int r = 0; r < 4; ++r) {
                    float p = exp2_raw(sc[ct][r] - mn);
                    pv[r] = f2b(p);
                    s0 += p;
                }
                *(short4v*)&Ps[w][l16 * 64 + (((ct * 2 + (lq >> 1)) ^ e) * 8) + (lq & 1) * 4] = pv;
            }
            s0 += __shfl_xor(s0, 16);
            s0 += __shfl_xor(s0, 32);
            if (skip) {
                l_s += s0;
            } else {
                float al = exp2_raw(m_s - mn);
                m_s = mn;
                l_s = l_s * al + s0;
                float albc[4];
#pragma unroll
                for (int r = 0; r < 4; ++r) albc[r] = __shfl(al, lq * 4 + r);
#pragma unroll
                for (int dt = 0; dt < 4; ++dt) {
                    f32x4 a4 = acc[dt];
                    a4[0] *= albc[0]; a4[1] *= albc[1]; a4[2] *= albc[2]; a4[3] *= albc[3];
                    acc[dt] = a4;
                }
            }
            __builtin_amdgcn_s_setprio(1);
#pragma unroll
            for (int kk = 0; kk < 2; ++kk) {
                short8 pa = *(const short8*)&Ps[w][l16 * 64 + (((kk * 4 + lq) ^ e) * 8)];
#pragma unroll
                for (int dt = 0; dt < 4; ++dt) {
                    short8 bv = *(const short8*)&Vc[(dt * 16 + l16) * 64 + (((kk * 4 + lq) ^ e) * 8)];
                    acc[dt] = __builtin_amdgcn_mfma_f32_16x16x32_bf16(pa, bv, acc[dt], 0, 0, 0);
                }
            }
            __builtin_amdgcn_s_setprio(0);
        }
        barrier_nodrain();
    }
    {
        float lbc[4];
#pragma unroll
        for (int r = 0; r < 4; ++r) lbc[r] = __shfl(l_s, lq * 4 + r);
#pragma unroll
        for (int r = 0; r < 4; ++r) {
            float inv = 1.0f / lbc[r];
            size_t ob = (size_t)((b * T_) + q0 + w * 16 + lq * 4 + r) * C_ + h * 64 + l16;
#pragma unroll
            for (int dt = 0; dt < 4; ++dt)
                att[ob + dt * 16] = f2b(acc[dt][r] * inv);
        }
    }
}

extern "C" void kernel_launch(void* const* d_in, const int* in_sizes, int n_in,
                              void* d_out, int out_size, void* d_ws, size_t ws_size,
                              hipStream_t stream) {
    const float* x = (const float*)d_in[0];
    const float* Wqkv = (const float*)d_in[1];
    const float* Wproj = (const float*)d_in[2];
    char* ws = (char*)d_ws;

    short* qkv = (short*)ws;                                     // [0, 48MB)
    short* att = (short*)(ws + (size_t)BT_ * NQKV * 2);          // [48MB, 64MB)
    short* wqb = att;                                            // 6MB, dead before att written
    float2* tab = (float2*)(ws + (size_t)BT_ * NQKV * 2 + (size_t)3 * C_ * C_ * 2); // 512KB
    short* wpb = qkv;                                            // 2MB, qkv dead after attn
    short* vT  = (short*)d_out;                                  // d_out[0,16MB): V^T scratch
    short* xb  = (short*)((char*)d_out + ((size_t)BT_ * C_ * 2)); // d_out[16,32MB): x bf16

    // 1) fused prep: x->bf16, Wqkv->bf16, rope table
    const int XB = (BT_ * C_) / 2048, WB = (3 * C_ * C_) / 2048;
    prep_kernel<<<XB + WB + 256, 256, 0, stream>>>(x, Wqkv, xb, wqb, tab);
    // 2) qkv = xb @ Wqkv^T with fused RoPE; V columns written transposed to vT
    dim3 g1(BT_ / 128, NQKV / 256);
    gemm_pipe<0, 1, 1><<<g1, 512, 0, stream>>>(xb, wqb, (void*)qkv, BT_, NQKV, C_, tab, vT);
    // 3) attention
    attn_mfma<<<B_ * H_ * (T_ / 128), 512, 0, stream>>>(qkv, vT, att);
    // 4) Wproj -> bf16
    cvt_kernel<<<(C_ * C_) / 2048, 256, 0, stream>>>(Wproj, wpb, C_ * C_);
    // 5) out = att @ Wproj^T (fp32 out; overwrites vT/xb scratch)
    dim3 g2(BT_ / 128, C_ / 256);
    gemm_pipe<1, 0, 0><<<g2, 512, 0, stream>>>(att, wpb, d_out, BT_, C_, C_, tab, nullptr);
}

// Round 16
// 152.453 us; speedup vs baseline: 1.3876x; 1.1750x over previous
//
#include <hip/hip_runtime.h>
#include <hip/hip_bf16.h>

#define B_   4
#define T_   2048
#define C_   1024
#define H_   16
#define BT_  (B_ * T_)      // 8192
#define NQKV (3 * C_)       // 3072

typedef __attribute__((ext_vector_type(8))) short short8;
typedef __attribute__((ext_vector_type(4))) short short4v;
typedef __attribute__((ext_vector_type(4))) float f32x4;

__device__ inline float b2f(short u) {
    unsigned int x = ((unsigned int)(unsigned short)u) << 16;
    float f;
    __builtin_memcpy(&f, &x, 4);
    return f;
}
__device__ inline short f2b(float f) {
    __hip_bfloat16 h = __float2bfloat16(f);
    unsigned short u;
    __builtin_memcpy(&u, &h, 2);
    return (short)u;
}
__device__ inline f32x4 fz4() { f32x4 z; z[0] = z[1] = z[2] = z[3] = 0.f; return z; }
__device__ inline float exp2_raw(float x) {   // bare v_exp_f32 (=2^x), no libm fixup
    float r;
    asm("v_exp_f32 %0, %1" : "=v"(r) : "v"(x));
    return r;
}

__device__ inline void load_lds16(const void* g, void* l) {
    __builtin_amdgcn_global_load_lds((const __attribute__((address_space(1))) unsigned int*)g,
                                     (__attribute__((address_space(3))) unsigned int*)l,
                                     16, 0, 0);
}
__device__ inline void barrier_nodrain() {
    __builtin_amdgcn_sched_barrier(0);
    __builtin_amdgcn_s_barrier();
    __builtin_amdgcn_sched_barrier(0);
}

__device__ inline void cvt8(const float* in, short* out, int i) {
    float4 a = *(const float4*)(in + i);
    float4 b = *(const float4*)(in + i + 4);
    short8 s;
    s[0] = f2b(a.x); s[1] = f2b(a.y); s[2] = f2b(a.z); s[3] = f2b(a.w);
    s[4] = f2b(b.x); s[5] = f2b(b.y); s[6] = f2b(b.z); s[7] = f2b(b.w);
    *(short8*)(out + i) = s;
}

// fp32 -> bf16 bulk convert (n multiple of 2048)
__global__ __launch_bounds__(256) void cvt_kernel(const float* __restrict__ in,
                                                  short* __restrict__ out, int n) {
    int i = (blockIdx.x * 256 + threadIdx.x) * 8;
    if (i >= n) return;
    cvt8(in, out, i);
}

// Fused prep: x->bf16 (4096 blocks), Wqkv->bf16 (1536 blocks), rope table (256 blocks)
__global__ __launch_bounds__(256) void prep_kernel(const float* __restrict__ x,
                                                   const float* __restrict__ Wqkv,
                                                   short* __restrict__ xb,
                                                   short* __restrict__ wqb,
                                                   float2* __restrict__ tab) {
    const int XB = (BT_ * C_) / 2048;        // 4096
    const int WB = (3 * C_ * C_) / 2048;     // 1536
    int bid = blockIdx.x;
    if (bid < XB) {
        cvt8(x, xb, (bid * 256 + threadIdx.x) * 8);
    } else if (bid < XB + WB) {
        cvt8(Wqkv, wqb, ((bid - XB) * 256 + threadIdx.x) * 8);
    } else {
        int idx = (bid - XB - WB) * 256 + threadIdx.x;   // 65536
        int t = idx >> 5, i = idx & 31;
        float inv = exp2f(-(float)i * 0.41524101186092029f);
        float ang = (float)t * inv;
        float s, c;
        sincosf(ang, &s, &c);
        tab[idx] = make_float2(c, s);
    }
}

// C[m][n] = sum_k A[m][k]*Bw[n][k]; A,Bw bf16 [.][K]. 128x128 block, BK=64,
// 4 waves (2Mx2N, 64x64 wave-tile), 256 threads. RING-2 LDS in one 64KB block
// (-> 2 blocks/CU for cross-block TLP overlap of barrier stalls), counted
// vmcnt(8) across raw barriers (R8-proven schedule), chunk-XOR swizzle.
// TRANSV: blocks with n0>=2048 (V cols) write TRANSPOSED to vT via LDS restage.
template <int CF32, int ROPE, int TRANSV>
__global__ __launch_bounds__(256) void gemm_pipe(const short* __restrict__ Ab,
                                                 const short* __restrict__ Bw,
                                                 void* __restrict__ Cp,
                                                 int M, int N, int K,
                                                 const float2* __restrict__ tab,
                                                 short* __restrict__ vT) {
    __shared__ short SH[2][2 * 128 * 64];   // [buf][A 8192 shorts | B 8192 shorts]
    const int tid = threadIdx.x;
    const int l16 = tid & 15, lq = (tid & 63) >> 4;
    const int wid = tid >> 6;                 // 0..3
    const int wm = wid >> 1, wn = wid & 1;    // 2M x 2N wave grid
    const int m0 = blockIdx.x * 128, n0 = blockIdx.y * 128;
    const int NT = K >> 6;

    f32x4 acc[4][4];
#pragma unroll
    for (int i = 0; i < 4; ++i)
#pragma unroll
        for (int j = 0; j < 4; ++j) acc[i][j] = fz4();

    auto stage = [&](int bf, int t) {   // 8 gload_lds per thread (4 A + 4 B)
        const int k0 = t * 64;
#pragma unroll
        for (int p = 0; p < 4; ++p) {   // A: 1024 chunks
            int c = p * 256 + tid;
            int r = c >> 3, cs = (c & 7) ^ (r & 7);
            load_lds16(Ab + (size_t)(m0 + r) * K + k0 + cs * 8,
                       &SH[bf][(p * 256 + (tid & ~63)) * 8]);
        }
#pragma unroll
        for (int p = 0; p < 4; ++p) {   // B: 1024 chunks
            int c = p * 256 + tid;
            int r = c >> 3, cs = (c & 7) ^ (r & 7);
            load_lds16(Bw + (size_t)(n0 + r) * K + k0 + cs * 8,
                       &SH[bf][8192 + (p * 256 + (tid & ~63)) * 8]);
        }
    };

    stage(0, 0);
    for (int t = 0; t < NT; ++t) {
        if (t + 1 < NT) {
            stage((t + 1) & 1, t + 1);
            asm volatile("s_waitcnt vmcnt(8)" ::: "memory");   // tile t landed; t+1 flying
        } else {
            asm volatile("s_waitcnt vmcnt(0)" ::: "memory");
        }
        barrier_nodrain();
        const short* Ac = &SH[t & 1][0];
        const short* Bc = &SH[t & 1][8192];
#pragma unroll
        for (int kk = 0; kk < 2; ++kk) {
            short8 af[4], bfr[4];
#pragma unroll
            for (int mf = 0; mf < 4; ++mf) {
                int row = wm * 64 + mf * 16 + l16;
                af[mf] = *(const short8*)&Ac[row * 64 + (((kk * 4 + lq) ^ (row & 7)) * 8)];
            }
#pragma unroll
            for (int nf = 0; nf < 4; ++nf) {
                int row = wn * 64 + nf * 16 + l16;
                bfr[nf] = *(const short8*)&Bc[row * 64 + (((kk * 4 + lq) ^ (row & 7)) * 8)];
            }
            __builtin_amdgcn_s_setprio(1);
#pragma unroll
            for (int mf = 0; mf < 4; ++mf)
#pragma unroll
                for (int nf = 0; nf < 4; ++nf)
                    acc[mf][nf] = __builtin_amdgcn_mfma_f32_16x16x32_bf16(
                        af[mf], bfr[nf], acc[mf][nf], 0, 0, 0);
            __builtin_amdgcn_s_setprio(0);
        }
        barrier_nodrain();   // readers done before next stage overwrites
    }

    if constexpr (TRANSV) {
        if (n0 >= 2048) {   // V columns: transposed write to vT via LDS restage
            short* Ld = &SH[0][0];       // 128 x 136 pad = 34.8KB; staging LDS dead
#pragma unroll
            for (int mf = 0; mf < 4; ++mf)
#pragma unroll
                for (int nf = 0; nf < 4; ++nf) {
                    int c = wn * 64 + nf * 16 + l16;
                    int tt = wm * 64 + mf * 16 + lq * 4;
                    short4v pv;
#pragma unroll
                    for (int rr = 0; rr < 4; ++rr) pv[rr] = f2b(acc[mf][nf][rr]);
                    *(short4v*)&Ld[c * 136 + tt] = pv;
                }
            barrier_nodrain();
            const int bb = m0 >> 11;     // batch
            const int t0 = m0 & 2047;
#pragma unroll
            for (int p = 0; p < 8; ++p) {
                int q = p * 256 + tid;   // 2048 16B chunks
                int c = q >> 4, tq = q & 15;
                short8 s = *(const short8*)&Ld[c * 136 + tq * 8];
                int cg = (n0 - 2048) + c;           // h*64+d within batch
                *(short8*)(vT + (size_t)(bb * 1024 + cg) * 2048 + t0 + tq * 8) = s;
            }
            return;
        }
    }
    if constexpr (ROPE) {
        if (n0 < 2048) {   // block-uniform: Q/K columns only
#pragma unroll
            for (int mf = 0; mf < 4; ++mf)
#pragma unroll
                for (int nf = 0; nf < 4; ++nf) {
                    const int ii = (nf * 16 + l16) >> 1;
                    const float sgn = (l16 & 1) ? 1.0f : -1.0f;
#pragma unroll
                    for (int rr = 0; rr < 4; ++rr) {
                        int row = m0 + wm * 64 + mf * 16 + lq * 4 + rr;
                        float v = acc[mf][nf][rr];
                        float p = __shfl_xor(v, 1);
                        float2 cs = tab[(row & (T_ - 1)) * 32 + ii];
                        acc[mf][nf][rr] = v * cs.x + sgn * (p * cs.y);
                    }
                }
        }
    }
#pragma unroll
    for (int mf = 0; mf < 4; ++mf)
#pragma unroll
        for (int nf = 0; nf < 4; ++nf)
#pragma unroll
            for (int rr = 0; rr < 4; ++rr) {
                int row = m0 + wm * 64 + mf * 16 + lq * 4 + rr;
                int col = n0 + wn * 64 + nf * 16 + l16;
                if constexpr (CF32)
                    ((float*)Cp)[(size_t)row * N + col] = acc[mf][nf][rr];
                else
                    ((short*)Cp)[(size_t)row * N + col] = f2b(acc[mf][nf][rr]);
            }
}

// MFMA flash attention: block = (b,h,128 q rows), 8 waves x 16 rows.
// Base-2 online softmax via raw v_exp_f32, defer-max THR=8, packed b64 P staging.
__global__ __launch_bounds__(512) void attn_mfma(const short* __restrict__ qkv,
                                                 const short* __restrict__ vT,
                                                 short* __restrict__ att) {
    const int blk = blockIdx.x;
    const int bh = blk & 63;               // all heads of a qt dispatch together
    const int qt = 15 - (blk >> 6);        // heavy q-tiles first
    const int b = bh >> 4, h = bh & 15;
    const int q0 = qt * 128;
    const int tid = threadIdx.x;
    const int w = tid >> 6, l = tid & 63;  // w: 0..7, 16 q-rows per wave
    const int l16 = l & 15, lq = l >> 4;
    const int e = l16 & 7;                 // row-XOR term for fragment reads

    __shared__ short Ks[2][64 * 64];
    __shared__ short Vs[2][64 * 64];
    __shared__ short Ps[8][16 * 64];

    short8 qf[2];
    {
        const size_t qrow = (size_t)((b * T_) + q0 + w * 16 + l16) * NQKV + h * 64;
#pragma unroll
        for (int kk = 0; kk < 2; ++kk) {
            short8 raw = *(const short8*)(qkv + qrow + kk * 32 + lq * 8);
            short8 s;
#pragma unroll
            for (int j = 0; j < 8; ++j) s[j] = f2b(0.18033688011112042f * b2f(raw[j])); // 0.125*log2e
            qf[kk] = s;
        }
    }
    f32x4 acc[4];
#pragma unroll
    for (int dt = 0; dt < 4; ++dt) acc[dt] = fz4();
    float m_s = -1e30f, l_s = 0.f;

    const int nt = 2 * qt + 2;
    const int qg_max = q0 + w * 16 + 15;   // wave's last q row
    auto stage = [&](int bf, int t) {      // 2 gload_lds per thread (512 threads)
        const int k0 = t * 64;
        const size_t kbase = (size_t)((b * T_) + k0) * NQKV + C_ + h * 64;
        const size_t vbase = (size_t)(bh * 64) * 2048 + k0;
        int r = tid >> 3;
        int cg = (tid & 7) ^ (r & 7);
        load_lds16(qkv + kbase + (size_t)r * NQKV + cg * 8, &Ks[bf][(tid & ~63) * 8]);
        load_lds16(vT + vbase + (size_t)r * 2048 + cg * 8, &Vs[bf][(tid & ~63) * 8]);
    };

    stage(0, 0);
    for (int t = 0; t < nt; ++t) {
        const int k0 = t * 64;
        if (t + 1 < nt) {
            stage((t + 1) & 1, t + 1);
            asm volatile("s_waitcnt vmcnt(2)" ::: "memory");
        } else {
            asm volatile("s_waitcnt vmcnt(0)" ::: "memory");
        }
        barrier_nodrain();
        const short* Kc = Ks[t & 1];
        const short* Vc = Vs[t & 1];
        if (k0 <= qg_max) {                // wave-uniform: tile has unmasked cols
            const int qg = q0 + w * 16 + l16;
            f32x4 sc[4];
#pragma unroll
            for (int ct = 0; ct < 4; ++ct) sc[ct] = fz4();
            __builtin_amdgcn_s_setprio(1);
#pragma unroll
            for (int kk = 0; kk < 2; ++kk)
#pragma unroll
                for (int ct = 0; ct < 4; ++ct) {
                    short8 ak = *(const short8*)&Kc[(ct * 16 + l16) * 64 + (((kk * 4 + lq) ^ e) * 8)];
                    sc[ct] = __builtin_amdgcn_mfma_f32_16x16x32_bf16(ak, qf[kk], sc[ct], 0, 0, 0);
                }
            __builtin_amdgcn_s_setprio(0);
            if (k0 + 63 > q0 + w * 16) {
#pragma unroll
                for (int ct = 0; ct < 4; ++ct)
#pragma unroll
                    for (int r = 0; r < 4; ++r)
                        if (k0 + ct * 16 + lq * 4 + r > qg) sc[ct][r] = -1e30f;
            }
            float mx = -1e30f;
#pragma unroll
            for (int ct = 0; ct < 4; ++ct)
#pragma unroll
                for (int r = 0; r < 4; ++r) mx = fmaxf(mx, sc[ct][r]);
            mx = fmaxf(mx, __shfl_xor(mx, 16));
            mx = fmaxf(mx, __shfl_xor(mx, 32));
            const bool skip = __all(mx <= m_s + 8.0f);
            const float mn = skip ? m_s : fmaxf(m_s, mx);
            float s0 = 0.f;
#pragma unroll
            for (int ct = 0; ct < 4; ++ct) {
                short4v pv;
#pragma unroll
                for (int r = 0; r < 4; ++r) {
                    float p = exp2_raw(sc[ct][r] - mn);
                    pv[r] = f2b(p);
                    s0 += p;
                }
                *(short4v*)&Ps[w][l16 * 64 + (((ct * 2 + (lq >> 1)) ^ e) * 8) + (lq & 1) * 4] = pv;
            }
            s0 += __shfl_xor(s0, 16);
            s0 += __shfl_xor(s0, 32);
            if (skip) {
                l_s += s0;
            } else {
                float al = exp2_raw(m_s - mn);
                m_s = mn;
                l_s = l_s * al + s0;
                float albc[4];
#pragma unroll
                for (int r = 0; r < 4; ++r) albc[r] = __shfl(al, lq * 4 + r);
#pragma unroll
                for (int dt = 0; dt < 4; ++dt) {
                    f32x4 a4 = acc[dt];
                    a4[0] *= albc[0]; a4[1] *= albc[1]; a4[2] *= albc[2]; a4[3] *= albc[3];
                    acc[dt] = a4;
                }
            }
            __builtin_amdgcn_s_setprio(1);
#pragma unroll
            for (int kk = 0; kk < 2; ++kk) {
                short8 pa = *(const short8*)&Ps[w][l16 * 64 + (((kk * 4 + lq) ^ e) * 8)];
#pragma unroll
                for (int dt = 0; dt < 4; ++dt) {
                    short8 bv = *(const short8*)&Vc[(dt * 16 + l16) * 64 + (((kk * 4 + lq) ^ e) * 8)];
                    acc[dt] = __builtin_amdgcn_mfma_f32_16x16x32_bf16(pa, bv, acc[dt], 0, 0, 0);
                }
            }
            __builtin_amdgcn_s_setprio(0);
        }
        barrier_nodrain();
    }
    {
        float lbc[4];
#pragma unroll
        for (int r = 0; r < 4; ++r) lbc[r] = __shfl(l_s, lq * 4 + r);
#pragma unroll
        for (int r = 0; r < 4; ++r) {
            float inv = 1.0f / lbc[r];
            size_t ob = (size_t)((b * T_) + q0 + w * 16 + lq * 4 + r) * C_ + h * 64 + l16;
#pragma unroll
            for (int dt = 0; dt < 4; ++dt)
                att[ob + dt * 16] = f2b(acc[dt][r] * inv);
        }
    }
}

extern "C" void kernel_launch(void* const* d_in, const int* in_sizes, int n_in,
                              void* d_out, int out_size, void* d_ws, size_t ws_size,
                              hipStream_t stream) {
    const float* x = (const float*)d_in[0];
    const float* Wqkv = (const float*)d_in[1];
    const float* Wproj = (const float*)d_in[2];
    char* ws = (char*)d_ws;

    short* qkv = (short*)ws;                                     // [0, 48MB)
    short* att = (short*)(ws + (size_t)BT_ * NQKV * 2);          // [48MB, 64MB)
    short* wqb = att;                                            // 6MB, dead before att written
    float2* tab = (float2*)(ws + (size_t)BT_ * NQKV * 2 + (size_t)3 * C_ * C_ * 2); // 512KB
    short* wpb = qkv;                                            // 2MB, qkv dead after attn
    short* vT  = (short*)d_out;                                  // d_out[0,16MB): V^T scratch
    short* xb  = (short*)((char*)d_out + ((size_t)BT_ * C_ * 2)); // d_out[16,32MB): x bf16

    // 1) fused prep: x->bf16, Wqkv->bf16, rope table
    const int XB = (BT_ * C_) / 2048, WB = (3 * C_ * C_) / 2048;
    prep_kernel<<<XB + WB + 256, 256, 0, stream>>>(x, Wqkv, xb, wqb, tab);
    // 2) qkv = xb @ Wqkv^T with fused RoPE; V columns written transposed to vT
    dim3 g1(BT_ / 128, NQKV / 128);
    gemm_pipe<0, 1, 1><<<g1, 256, 0, stream>>>(xb, wqb, (void*)qkv, BT_, NQKV, C_, tab, vT);
    // 3) attention
    attn_mfma<<<B_ * H_ * (T_ / 128), 512, 0, stream>>>(qkv, vT, att);
    // 4) Wproj -> bf16
    cvt_kernel<<<(C_ * C_) / 2048, 256, 0, stream>>>(Wproj, wpb, C_ * C_);
    // 5) out = att @ Wproj^T (fp32 out; overwrites vT/xb scratch)
    dim3 g2(BT_ / 128, C_ / 128);
    gemm_pipe<1, 0, 0><<<g2, 256, 0, stream>>>(att, wpb, d_out, BT_, C_, C_, tab, nullptr);
}